// Round 3
// baseline (5186.640 us; speedup 1.0000x reference)
//
#include <hip/hip_runtime.h>
#include <hip/hip_fp16.h>
#include <cstdint>
#include <cstddef>

#define T_STEPS 256
#define K_DIM 2048
#define ROWS 64          // rows per pair (pair = 2 blocks splitting K columns)
#define NCW 8            // compute waves; wave 8 = communication wave
#define NT_W 8           // ntiles (16 cols) per compute wave: 128 cols, 1024/block
#define REG_NT 4         // ntiles per wave in VGPRs
#define LDS_NT 4         // ntiles per wave in LDS (128 KB)

typedef _Float16 f16;
typedef _Float16 f16x8 __attribute__((ext_vector_type(8)));
typedef float f32x4 __attribute__((ext_vector_type(4)));

// LDS layout (static so the compiler sees true occupancy: 1 block/CU)
#define W1S_OFF 0        // 8 waves * 4 nt * 4 ks * 64 lanes * 16B = 131072
#define U_OFF   131072   // u [64 rows][64 cols] f16 swizzled = 8192
#define Y_OFF   139264   // y [2][64 rows][64 cols] f16 swizzled = 16384
#define PB_OFF  155648   // predbuf f32[8][64] = 2048
#define FLAG_OFF 157696  // unsigned step tag
#define SMEM_BYTES 157712

// workspace layout
#define W1P_BYTES (128 * 4 * 64 * 16)            // 524288: packed fp16 W1
#define MBOX_OFF  W1P_BYTES                      // u64[256][2][64] = 262144
#define MBOX_BYTES (256 * 2 * 64 * 8)

// Pack W1 [128][2048] f32 row-major into fp16 MFMA-B-fragment layout:
// w1p[((ntile*4 + ks)*64 + lane)*8 + i] = W1[ks*32 + (lane>>4)*8 + i][ntile*16 + (lane&15)]
__global__ void __launch_bounds__(64) prepack_w1(const float* __restrict__ W1,
                                                 f16* __restrict__ w1p) {
  int blk = blockIdx.x;            // 0..511 = ntile*4 + ks
  int ntile = blk >> 2, ks = blk & 3;
  int lane = threadIdx.x;
  int col = ntile * 16 + (lane & 15);
  int kb = ks * 32 + ((lane >> 4) << 3);
  f16x8 pk;
#pragma unroll
  for (int i = 0; i < 8; ++i) pk[i] = (f16)W1[(size_t)(kb + i) * K_DIM + col];
  ((f16x8*)w1p)[(ntile * 4 + ks) * 64 + lane] = pk;
}

__global__ void __launch_bounds__(576, 3)
rnn_fused(const float* __restrict__ u, const float* __restrict__ y0,
          const f16* __restrict__ w1p, const float* __restrict__ b1,
          const float* __restrict__ w2, const float* __restrict__ b2,
          float* __restrict__ out, unsigned long long* mbox)
{
  __shared__ __align__(16) char smem[SMEM_BYTES];
  f16x8* w1s     = (f16x8*)(smem + W1S_OFF);
  float* predbuf = (float*)(smem + PB_OFF);
  unsigned* flagw = (unsigned*)(smem + FLAG_OFF);

  const int tid = threadIdx.x, lane = tid & 63, wave = tid >> 6;
  const int b = blockIdx.x;
  const int jj_ = b >> 3;
  const int half = jj_ & 1;                 // which K-half of W1
  const int pair = ((b & 7) << 4) | (jj_ >> 1);
  const int partner = b ^ 8;                // same XCD residue under %8 round-robin
  const int row0 = pair * ROWS;
  const int colbase = half * 1024;
  const float b2v = b2[0];
  const f16x8* w1pv = (const f16x8*)w1p;
  const float TWO_L = 2.885390081777927f;   // 2*log2(e)

  // ---- per-wave setup (compute waves only; wave 8 indices would be OOB) ----
  float b1x[NT_W], w2v[NT_W];
  f16x8 w1r[REG_NT * 4];
  if (wave < NCW) {
#pragma unroll
    for (int nt = 0; nt < NT_W; ++nt) {
      int col = colbase + wave * 128 + nt * 16 + (lane & 15);
      b1x[nt] = TWO_L * b1[col];
      w2v[nt] = w2[col];
    }
#pragma unroll
    for (int nt = 0; nt < REG_NT; ++nt)
#pragma unroll
      for (int ks = 0; ks < 4; ++ks)
        w1r[nt * 4 + ks] = w1pv[((half * 64 + wave * 8 + nt) * 4 + ks) * 64 + lane];
#pragma unroll
    for (int i = 0; i < REG_NT * 4; ++i) asm volatile("" : "+v"(w1r[i]));
#pragma unroll
    for (int nt = 0; nt < LDS_NT; ++nt)
#pragma unroll
      for (int ks = 0; ks < 4; ++ks)
        w1s[((wave * LDS_NT + nt) * 4 + ks) * 64 + lane] =
            w1pv[((half * 64 + wave * 8 + REG_NT + nt) * 4 + ks) * 64 + lane];
  }

  // comm wave: Chalf = sum of w2 over this block's 1024 cols
  float Chalf = 0.f;
  if (wave == NCW) {
    float s = 0.f;
#pragma unroll
    for (int i = 0; i < 16; ++i) s += w2[colbase + lane * 16 + i];
    s += __shfl_xor(s, 1);  s += __shfl_xor(s, 2);  s += __shfl_xor(s, 4);
    s += __shfl_xor(s, 8);  s += __shfl_xor(s, 16); s += __shfl_xor(s, 32);
    Chalf = s;
  }
  if (tid == 0) *flagw = 0u;   // step-0 state (y0 col0) is loaded directly

  // ---- init: y0 -> y[0] (col0 included), u_0 -> u region, prefetch u_1 ----
  float4 up0, up1;
  if (tid < 512) {
    int r = tid >> 3, j0 = (tid & 7) * 8;
    {
      const float4* yp = (const float4*)(y0 + (size_t)(row0 + r) * 64 + j0);
      float4 a = yp[0], c = yp[1];
      f16x8 pk;
      pk[0] = (f16)a.x; pk[1] = (f16)a.y; pk[2] = (f16)a.z; pk[3] = (f16)a.w;
      pk[4] = (f16)c.x; pk[5] = (f16)c.y; pk[6] = (f16)c.z; pk[7] = (f16)c.w;
      int byte = (r * 128 + j0 * 2) ^ ((r & 7) << 4);
      *(f16x8*)(smem + Y_OFF + byte) = pk;     // y[par=0]
    }
    {
      const float4* p = (const float4*)(u + ((size_t)(row0 + r) * T_STEPS + 0) * 64 + j0);
      float4 a = p[0], c = p[1];
      f16x8 pk;
      pk[0] = (f16)a.x; pk[1] = (f16)a.y; pk[2] = (f16)a.z; pk[3] = (f16)a.w;
      pk[4] = (f16)c.x; pk[5] = (f16)c.y; pk[6] = (f16)c.z; pk[7] = (f16)c.w;
      int byte = (r * 128 + j0 * 2) ^ ((r & 7) << 4);
      *(f16x8*)(smem + U_OFF + byte) = pk;
    }
    const float4* p1 = (const float4*)(u + ((size_t)(row0 + r) * T_STEPS + 1) * 64 + j0);
    up0 = p1[0]; up1 = p1[1];
  }
  __syncthreads();   // X valid for t=0

  float contrib = 0.f;   // comm wave: this block's half-sum from previous step

  for (int t = 0; t < T_STEPS; ++t) {
    const int par = t & 1;

    if (wave == NCW) {
      // ---- comm wave: finalize pred_{t-1}, publish into y[par] col0 + flag.
      //      Partner posted its half after its barrier A of step t-1 (half a
      //      step ago) -> poll is ~1 iteration. ----
      if (t > 0) {
        const unsigned want = (unsigned)t;
        unsigned long long pv;
        do {
          pv = __hip_atomic_load(&mbox[((size_t)(partner * 2 + ((t - 1) & 1))) * 64 + lane],
                                 __ATOMIC_RELAXED, __HIP_MEMORY_SCOPE_AGENT);
        } while ((unsigned)(pv >> 32) != want);
        float pc = __builtin_bit_cast(float, (unsigned)(pv & 0xffffffffu));
        float ps = contrib + pc + b2v;
        if (half == 0) out[(size_t)(row0 + lane) * T_STEPS + (t - 1)] = ps;
        int byte = (lane * 128) ^ ((lane & 7) << 4);
        *(f16*)(smem + Y_OFF + par * 8192 + byte) = (f16)ps;
        __hip_atomic_store(flagw, (unsigned)t, __ATOMIC_RELEASE,
                           __HIP_MEMORY_SCOPE_WORKGROUP);
      }
    } else {
      // ---- compute waves: gate on flag (normally already set), then GEMM ----
      while (__hip_atomic_load(flagw, __ATOMIC_ACQUIRE, __HIP_MEMORY_SCOPE_WORKGROUP) !=
             (unsigned)t) {}

      // A-fragments for 64 rows (u region ks0-1, y[par] region ks2-3)
      f16x8 af[4][4];
      {
        const char* ubase = smem + U_OFF;
        const char* ybase = smem + Y_OFF + par * 8192;
        int koff = (lane >> 4) << 4;
#pragma unroll
        for (int mt = 0; mt < 4; ++mt) {
          int r = mt * 16 + (lane & 15);
          int base = r * 128 + koff, sw = (r & 7) << 4;
          af[mt][0] = *(const f16x8*)(ubase + (base ^ sw));
          af[mt][1] = *(const f16x8*)(ubase + ((base + 64) ^ sw));
          af[mt][2] = *(const f16x8*)(ybase + (base ^ sw));
          af[mt][3] = *(const f16x8*)(ybase + ((base + 64) ^ sw));
        }
      }

      auto mfma_nt = [&](int nt, f32x4* acc) {
#pragma unroll
        for (int mt = 0; mt < 4; ++mt) acc[mt] = (f32x4){0.f, 0.f, 0.f, 0.f};
#pragma unroll
        for (int ks = 0; ks < 4; ++ks) {
          f16x8 bf = (nt < REG_NT)
                         ? w1r[nt * 4 + ks]
                         : w1s[((wave * LDS_NT + (nt - REG_NT)) * 4 + ks) * 64 + lane];
#pragma unroll
          for (int mt = 0; mt < 4; ++mt)
            acc[mt] = __builtin_amdgcn_mfma_f32_16x16x32_f16(af[mt][ks], bf, acc[mt], 0, 0, 0);
        }
      };

      float predp[4][4];
#pragma unroll
      for (int mt = 0; mt < 4; ++mt)
#pragma unroll
        for (int jj = 0; jj < 4; ++jj) predp[mt][jj] = 0.f;

      // epilogue: S += w2 * rcp(1 + exp2(2L*s + 2L*b1));  h = 1 - 2*rcp
      auto epi = [&](int nt, f32x4* acc) {
#pragma unroll
        for (int mt = 0; mt < 4; ++mt)
#pragma unroll
          for (int jj = 0; jj < 4; ++jj) {
            float e  = __builtin_amdgcn_exp2f(fmaf(TWO_L, acc[mt][jj], b1x[nt]));
            float rr = __builtin_amdgcn_rcpf(1.0f + e);
            predp[mt][jj] = fmaf(w2v[nt], rr, predp[mt][jj]);
          }
      };

      // software-pipelined GEMM/epilogue: every epilogue has an independent
      // MFMA group in flight on the matrix pipe
      f32x4 accA[4], accB[4];
      mfma_nt(0, accA);
      mfma_nt(1, accB);
      epi(0, accA); mfma_nt(2, accA);
      epi(1, accB); mfma_nt(3, accB);
      epi(2, accA); mfma_nt(4, accA);
      epi(3, accB); mfma_nt(5, accB);
      epi(4, accA); mfma_nt(6, accA);
      epi(5, accB); mfma_nt(7, accB);
      epi(6, accA);
      epi(7, accB);

      // wave reduce over the 16 col-lanes
#pragma unroll
      for (int mt = 0; mt < 4; ++mt)
#pragma unroll
        for (int jj = 0; jj < 4; ++jj) {
          float v = predp[mt][jj];
          v += __shfl_xor(v, 1); v += __shfl_xor(v, 2);
          v += __shfl_xor(v, 4); v += __shfl_xor(v, 8);
          if ((lane & 15) == 0)
            predbuf[wave * 64 + mt * 16 + ((lane >> 4) << 2) + jj] = v;
        }
    }
    __syncthreads();  // [A] predbuf ready; X fully read for step t

    if (wave == NCW) {
      // post own half-sum for pred_t (partner consumes at its step t+1)
      float own = 0.f;
#pragma unroll
      for (int w = 0; w < NCW; ++w) own += predbuf[w * 64 + lane];
      contrib = fmaf(-2.0f, own, Chalf);
      unsigned long long val =
          ((unsigned long long)(unsigned)(t + 1) << 32) |
          (unsigned long long)__builtin_bit_cast(unsigned, contrib);
      __hip_atomic_store(&mbox[((size_t)(b * 2 + par)) * 64 + lane], val,
                         __ATOMIC_RELAXED, __HIP_MEMORY_SCOPE_AGENT);
    } else {
      // ---- y shift into other parity buffer, u_{t+1} write, u_{t+2} prefetch.
      //      col0 of y[par] holds pred_{t-1} (comm wrote it), so the generic
      //      shift propagates it to col1; new col0 is a placeholder the comm
      //      wave overwrites with pred_t at the top of step t+1. ----
      int r3 = tid >> 3, j0 = (tid & 7) * 8;
      int sw3 = (r3 & 7) << 4;
      const char* yp = smem + Y_OFF + par * 8192;
      char*       yn = smem + Y_OFF + (par ^ 1) * 8192;
      f16x8 chB = *(const f16x8*)(yp + ((r3 * 128 + j0 * 2) ^ sw3));
      f16x8 nw;
      nw[0] = j0 ? *(const f16*)(yp + ((r3 * 128 + j0 * 2 - 2) ^ sw3)) : (f16)0.f;
#pragma unroll
      for (int i = 1; i < 8; ++i) nw[i] = chB[i - 1];
      *(f16x8*)(yn + ((r3 * 128 + j0 * 2) ^ sw3)) = nw;

      if (t + 1 < T_STEPS) {
        f16x8 pk;
        pk[0] = (f16)up0.x; pk[1] = (f16)up0.y; pk[2] = (f16)up0.z; pk[3] = (f16)up0.w;
        pk[4] = (f16)up1.x; pk[5] = (f16)up1.y; pk[6] = (f16)up1.z; pk[7] = (f16)up1.w;
        *(f16x8*)(smem + U_OFF + ((r3 * 128 + j0 * 2) ^ sw3)) = pk;
      }
      if (t + 2 < T_STEPS) {
        const float4* p =
            (const float4*)(u + ((size_t)(row0 + r3) * T_STEPS + t + 2) * 64 + j0);
        up0 = p[0]; up1 = p[1];
      }
    }
    __syncthreads();  // [C] X valid for step t+1
  }

  // flush the final prediction (t = 255)
  if (wave == NCW) {
    const unsigned want = (unsigned)T_STEPS;
    unsigned long long pv;
    do {
      pv = __hip_atomic_load(&mbox[((size_t)(partner * 2 + 1)) * 64 + lane],
                             __ATOMIC_RELAXED, __HIP_MEMORY_SCOPE_AGENT);
    } while ((unsigned)(pv >> 32) != want);
    float pc = __builtin_bit_cast(float, (unsigned)(pv & 0xffffffffu));
    float ps = contrib + pc + b2v;
    if (half == 0) out[(size_t)(row0 + lane) * T_STEPS + (T_STEPS - 1)] = ps;
  }
}

extern "C" void kernel_launch(void* const* d_in, const int* in_sizes, int n_in,
                              void* d_out, int out_size, void* d_ws, size_t ws_size,
                              hipStream_t stream) {
  const float* u  = (const float*)d_in[0];
  const float* y0 = (const float*)d_in[1];
  const float* W1 = (const float*)d_in[2];
  const float* b1 = (const float*)d_in[3];
  const float* W2 = (const float*)d_in[4];
  const float* b2 = (const float*)d_in[5];

  f16* w1p = (f16*)d_ws;
  unsigned long long* mbox = (unsigned long long*)((char*)d_ws + MBOX_OFF);

  // mailboxes must be zero at every launch (stale tags from a previous replay
  // would alias tags of this launch)
  hipMemsetAsync((char*)d_ws + MBOX_OFF, 0, MBOX_BYTES, stream);

  prepack_w1<<<512, 64, 0, stream>>>(W1, w1p);

  rnn_fused<<<256, 576, 0, stream>>>(u, y0, w1p, b1, W2, b2, (float*)d_out, mbox);
}

// Round 4
// 2097.006 us; speedup vs baseline: 2.4734x; 2.4734x over previous
//
#include <hip/hip_runtime.h>
#include <hip/hip_fp16.h>
#include <cstdint>
#include <cstddef>

#define T_STEPS 256
#define K_DIM 2048
#define NCW 8            // 8 compute waves, 512 threads
#define NT_W 8           // ntiles (16 cols) per wave: 128 cols, 1024/block
#define REG_NT 4         // ntiles per wave in VGPRs
#define LDS_NT 4         // ntiles per wave in LDS (128 KB)

typedef _Float16 f16;
typedef _Float16 f16x8 __attribute__((ext_vector_type(8)));
typedef _Float16 f16x4 __attribute__((ext_vector_type(4)));
typedef float f32x4 __attribute__((ext_vector_type(4)));

// LDS layout (static: 1 block/CU)
#define W1S_OFF 0        // 8 waves * 4 nt * 4 ks * 64 lanes * 16B = 131072
#define U_OFF   131072   // u [2 group][32 rows][64 cols] f16 swizzled = 8192
#define Y_OFF   139264   // y [2 group][2 par][32 rows][64 cols] f16 = 16384
#define PB_OFF  155648   // predbuf f32[8][32] = 1024
#define SMEM_BYTES 156672

// workspace layout (786432 B total, same as round 0)
#define W1P_BYTES (128 * 4 * 64 * 16)            // 524288: packed fp16 W1
#define MBOX_OFF  W1P_BYTES
#define MBOX_BYTES (256 * 2 * 2 * 32 * 8)        // [block][group][slot][32] u64 = 262144

// Pack W1 [128][2048] f32 row-major into fp16 MFMA-B-fragment layout:
// w1p[((ntile*4 + ks)*64 + lane)*8 + i] = W1[ks*32 + (lane>>4)*8 + i][ntile*16 + (lane&15)]
__global__ void __launch_bounds__(64) prepack_w1(const float* __restrict__ W1,
                                                 f16* __restrict__ w1p) {
  int blk = blockIdx.x;            // 0..511 = ntile*4 + ks
  int ntile = blk >> 2, ks = blk & 3;
  int lane = threadIdx.x;
  int col = ntile * 16 + (lane & 15);
  int kb = ks * 32 + ((lane >> 4) << 3);
  f16x8 pk;
#pragma unroll
  for (int i = 0; i < 8; ++i) pk[i] = (f16)W1[(size_t)(kb + i) * K_DIM + col];
  ((f16x8*)w1p)[(ntile * 4 + ks) * 64 + lane] = pk;
}

__global__ void __launch_bounds__(512, 2)
__attribute__((amdgpu_waves_per_eu(2, 2)))
rnn_fused(const float* __restrict__ u, const float* __restrict__ y0,
          const f16* __restrict__ w1p, const float* __restrict__ b1,
          const float* __restrict__ w2, const float* __restrict__ b2,
          float* __restrict__ out, unsigned long long* mbox)
{
  __shared__ __align__(16) char smem[SMEM_BYTES];
  f16x8* w1s     = (f16x8*)(smem + W1S_OFF);
  float* predbuf = (float*)(smem + PB_OFF);

  const int tid = threadIdx.x, lane = tid & 63, wave = tid >> 6;
  const int b = blockIdx.x;
  const int jj_ = b >> 3;
  const int half = jj_ & 1;                 // which K-half of W1
  const int pair = ((b & 7) << 4) | (jj_ >> 1);
  const int partner = b ^ 8;
  const int row0 = pair * 64;
  const int colbase = half * 1024;
  const float b2v = b2[0];
  const f16x8* w1pv = (const f16x8*)w1p;
  const float TWO_L = 2.885390081777927f;   // 2*log2(e)

  // per-lane epilogue constants
  float b1x[NT_W], w2v[NT_W];
#pragma unroll
  for (int nt = 0; nt < NT_W; ++nt) {
    int col = colbase + wave * 128 + nt * 16 + (lane & 15);
    b1x[nt] = TWO_L * b1[col];
    w2v[nt] = w2[col];
  }

  // Chalf = sum of w2 over this block's 1024 cols (wave 0, register-resident)
  float Chalf = 0.f;
  if (wave == 0) {
    float s = 0.f;
#pragma unroll
    for (int i = 0; i < 16; ++i) s += w2[colbase + lane * 16 + i];
    s += __shfl_xor(s, 1);  s += __shfl_xor(s, 2);  s += __shfl_xor(s, 4);
    s += __shfl_xor(s, 8);  s += __shfl_xor(s, 16); s += __shfl_xor(s, 32);
    Chalf = s;
  }

  // resident W1: 4 ntiles/wave in VGPRs, 4 in LDS
  f16x8 w1r[REG_NT * 4];
#pragma unroll
  for (int nt = 0; nt < REG_NT; ++nt)
#pragma unroll
    for (int ks = 0; ks < 4; ++ks)
      w1r[nt * 4 + ks] = w1pv[((half * 64 + wave * 8 + nt) * 4 + ks) * 64 + lane];
#pragma unroll
  for (int i = 0; i < REG_NT * 4; ++i) asm volatile("" : "+v"(w1r[i]));
#pragma unroll
  for (int nt = 0; nt < LDS_NT; ++nt)
#pragma unroll
    for (int ks = 0; ks < 4; ++ks)
      w1s[((wave * LDS_NT + nt) * 4 + ks) * 64 + lane] =
          w1pv[((half * 64 + wave * 8 + REG_NT + nt) * 4 + ks) * 64 + lane];

  // ---- init: both groups' y0 -> y[g][0] (col0 = y0[:,0] directly for t=0),
  //      u_0 -> U[g], prefetch u_1 into regs ----
  const int r_i = tid >> 4;                 // 0..31
  const int j0c = (tid & 15) * 4;           // 4 cols per thread
  const int sw_i = (r_i & 7) << 4;
  float4 upA, upB;                          // u_{t+1} prefetch, G0/G1
#pragma unroll
  for (int g = 0; g < 2; ++g) {
    int row = row0 + g * 32 + r_i;
    {
      float4 a = *(const float4*)(y0 + (size_t)row * 64 + j0c);
      f16x4 pk; pk[0] = (f16)a.x; pk[1] = (f16)a.y; pk[2] = (f16)a.z; pk[3] = (f16)a.w;
      *(f16x4*)(smem + Y_OFF + (g * 2 + 0) * 4096 + ((r_i * 128 + j0c * 2) ^ sw_i)) = pk;
    }
    {
      float4 a = *(const float4*)(u + ((size_t)row * T_STEPS + 0) * 64 + j0c);
      f16x4 pk; pk[0] = (f16)a.x; pk[1] = (f16)a.y; pk[2] = (f16)a.z; pk[3] = (f16)a.w;
      *(f16x4*)(smem + U_OFF + g * 4096 + ((r_i * 128 + j0c * 2) ^ sw_i)) = pk;
    }
    float4 p1 = *(const float4*)(u + ((size_t)row * T_STEPS + 1) * 64 + j0c);
    if (g == 0) upA = p1; else upB = p1;
  }
  __syncthreads();   // X valid for t=0, both groups

  float contrib0 = 0.f, contrib1 = 0.f;   // wave0: own half-sums per group

  // ================= phase = one step of one 32-row group =================
  auto phase = [&](int g, int t) {
    const int par = t & 1;
    const char* ubase = smem + U_OFF + g * 4096;
    const char* ybase = smem + Y_OFF + (g * 2 + par) * 4096;

    // A-fragments for 32 rows (u: ks0-1, y: ks2-3)
    f16x8 af[2][4];
    {
      int koff = (lane >> 4) << 4;
#pragma unroll
      for (int mt = 0; mt < 2; ++mt) {
        int r = mt * 16 + (lane & 15);
        int base = r * 128 + koff, sw = (r & 7) << 4;
        af[mt][0] = *(const f16x8*)(ubase + (base ^ sw));
        af[mt][1] = *(const f16x8*)(ubase + ((base + 64) ^ sw));
        af[mt][2] = *(const f16x8*)(ybase + (base ^ sw));
        af[mt][3] = *(const f16x8*)(ybase + ((base + 64) ^ sw));
      }
    }

    auto mfma_nt = [&](int nt, f32x4* acc) {
      acc[0] = (f32x4){0.f, 0.f, 0.f, 0.f};
      acc[1] = (f32x4){0.f, 0.f, 0.f, 0.f};
#pragma unroll
      for (int ks = 0; ks < 4; ++ks) {
        f16x8 bf = (nt < REG_NT)
                       ? w1r[nt * 4 + ks]
                       : w1s[((wave * LDS_NT + (nt - REG_NT)) * 4 + ks) * 64 + lane];
        acc[0] = __builtin_amdgcn_mfma_f32_16x16x32_f16(af[0][ks], bf, acc[0], 0, 0, 0);
        acc[1] = __builtin_amdgcn_mfma_f32_16x16x32_f16(af[1][ks], bf, acc[1], 0, 0, 0);
      }
    };

    float predp[2][4];
#pragma unroll
    for (int mt = 0; mt < 2; ++mt)
#pragma unroll
      for (int jj = 0; jj < 4; ++jj) predp[mt][jj] = 0.f;

    // epilogue: S += w2 * rcp(1 + exp2(2L*s + 2L*b1))
    auto epi = [&](int nt, f32x4* acc) {
#pragma unroll
      for (int mt = 0; mt < 2; ++mt)
#pragma unroll
        for (int jj = 0; jj < 4; ++jj) {
          float e  = __builtin_amdgcn_exp2f(fmaf(TWO_L, acc[mt][jj], b1x[nt]));
          float rr = __builtin_amdgcn_rcpf(1.0f + e);
          predp[mt][jj] = fmaf(w2v[nt], rr, predp[mt][jj]);
        }
    };

    // pipelined GEMM/epilogue (accA: even nt, accB: odd nt)
    f32x4 accA[2], accB[2];
    mfma_nt(0, accA);
    mfma_nt(1, accB);
    epi(0, accA); mfma_nt(2, accA);
    epi(1, accB); mfma_nt(3, accB);
    epi(2, accA); mfma_nt(4, accA);
    epi(3, accB); mfma_nt(5, accB);
    epi(4, accA); mfma_nt(6, accA);
    epi(5, accB); mfma_nt(7, accB);
    epi(6, accA);
    epi(7, accB);

    // wave reduce over the 16 col-lanes -> per-row partials
#pragma unroll
    for (int mt = 0; mt < 2; ++mt)
#pragma unroll
      for (int jj = 0; jj < 4; ++jj) {
        float v = predp[mt][jj];
        v += __shfl_xor(v, 1); v += __shfl_xor(v, 2);
        v += __shfl_xor(v, 4); v += __shfl_xor(v, 8);
        if ((lane & 15) == 0)
          predbuf[wave * 32 + mt * 16 + ((lane >> 4) << 2) + jj] = v;
      }
    __syncthreads();  // [A] predbuf ready; y[g][par] fully read

    // wave0: post this group's half-sum IMMEDIATELY (partner polls it
    // one phase later -> MALL latency hidden under the other group's GEMM)
    if (wave == 0 && lane < 32) {
      float own = 0.f;
#pragma unroll
      for (int w = 0; w < NCW; ++w) own += predbuf[w * 32 + lane];
      float c = fmaf(-2.0f, own, Chalf);
      if (g == 0) contrib0 = c; else contrib1 = c;
      unsigned long long val =
          ((unsigned long long)(unsigned)(t + 1) << 32) |
          (unsigned long long)__builtin_bit_cast(unsigned, c);
      __hip_atomic_store(&mbox[((size_t)((b * 2 + g) * 2 + par)) * 32 + lane], val,
                         __ATOMIC_RELAXED, __HIP_MEMORY_SCOPE_AGENT);
    }

    // ---- tail (all 512 threads): y-shift g -> y[g][par^1], u_{t+1} write,
    //      u_{t+2} prefetch.  16 threads/row, 4 cols each. ----
    {
      const char* yp = smem + Y_OFF + (g * 2 + par) * 4096;
      char*       yn = smem + Y_OFF + (g * 2 + (par ^ 1)) * 4096;
      f16x4 chB = *(const f16x4*)(yp + ((r_i * 128 + j0c * 2) ^ sw_i));
      f16x4 nw;
      nw[0] = j0c ? *(const f16*)(yp + ((r_i * 128 + j0c * 2 - 2) ^ sw_i)) : (f16)0.f;
      nw[1] = chB[0]; nw[2] = chB[1]; nw[3] = chB[2];
      *(f16x4*)(yn + ((r_i * 128 + j0c * 2) ^ sw_i)) = nw;

      if (t + 1 < T_STEPS) {
        float4 up = (g == 0) ? upA : upB;
        f16x4 pk; pk[0] = (f16)up.x; pk[1] = (f16)up.y; pk[2] = (f16)up.z; pk[3] = (f16)up.w;
        *(f16x4*)(smem + U_OFF + g * 4096 + ((r_i * 128 + j0c * 2) ^ sw_i)) = pk;
      }
      if (t + 2 < T_STEPS) {
        float4 p = *(const float4*)(
            u + ((size_t)(row0 + g * 32 + r_i) * T_STEPS + (t + 2)) * 64 + j0c);
        if (g == 0) upA = p; else upB = p;
      }
    }

    // ---- wave0: poll the OTHER group's exchange (posted one phase ago),
    //      publish pred into its y col0 + out store ----
    const bool need = (g == 1) || (t > 0);
    if (wave == 0 && lane < 32 && need) {
      const int gp = g ^ 1;
      const unsigned want = (g == 0) ? (unsigned)t : (unsigned)(t + 1);
      const int slot = (g == 0) ? ((t - 1) & 1) : (t & 1);
      const int pubpar = (g == 0) ? (t & 1) : ((t + 1) & 1);
      const int outcol = (g == 0) ? (t - 1) : t;
      unsigned long long pv;
      const unsigned long long* mb =
          &mbox[((size_t)((partner * 2 + gp) * 2 + slot)) * 32 + lane];
      do {
        pv = __hip_atomic_load(mb, __ATOMIC_RELAXED, __HIP_MEMORY_SCOPE_AGENT);
      } while ((unsigned)(pv >> 32) != want);
      float pc = __builtin_bit_cast(float, (unsigned)(pv & 0xffffffffu));
      float ps = ((g == 0) ? contrib1 : contrib0) + pc + b2v;
      *(f16*)(smem + Y_OFF + (gp * 2 + pubpar) * 4096 +
              ((lane * 128) ^ ((lane & 7) << 4))) = (f16)ps;
      if (half == 0)
        out[(size_t)(row0 + gp * 32 + lane) * T_STEPS + outcol] = ps;
    }
    __syncthreads();  // [C] y[g][par^1], U[g], published col0 all valid
  };
  // ========================================================================

  for (int t = 0; t < T_STEPS; ++t) {
    phase(0, t);
    phase(1, t);
  }

  // flush: G1's pred_255 (posted at phase(G1,255), never published in-loop)
  if (wave == 0 && lane < 32) {
    const unsigned want = (unsigned)T_STEPS;
    unsigned long long pv;
    const unsigned long long* mb =
        &mbox[((size_t)((partner * 2 + 1) * 2 + 1)) * 32 + lane];
    do {
      pv = __hip_atomic_load(mb, __ATOMIC_RELAXED, __HIP_MEMORY_SCOPE_AGENT);
    } while ((unsigned)(pv >> 32) != want);
    float pc = __builtin_bit_cast(float, (unsigned)(pv & 0xffffffffu));
    float ps = contrib1 + pc + b2v;
    if (half == 0)
      out[(size_t)(row0 + 32 + lane) * T_STEPS + (T_STEPS - 1)] = ps;
  }
}

extern "C" void kernel_launch(void* const* d_in, const int* in_sizes, int n_in,
                              void* d_out, int out_size, void* d_ws, size_t ws_size,
                              hipStream_t stream) {
  const float* u  = (const float*)d_in[0];
  const float* y0 = (const float*)d_in[1];
  const float* W1 = (const float*)d_in[2];
  const float* b1 = (const float*)d_in[3];
  const float* W2 = (const float*)d_in[4];
  const float* b2 = (const float*)d_in[5];

  f16* w1p = (f16*)d_ws;
  unsigned long long* mbox = (unsigned long long*)((char*)d_ws + MBOX_OFF);

  // mailboxes must be zero at every launch (graph replay re-runs this)
  hipMemsetAsync((char*)d_ws + MBOX_OFF, 0, MBOX_BYTES, stream);

  prepack_w1<<<512, 64, 0, stream>>>(W1, w1p);

  rnn_fused<<<256, 512, 0, stream>>>(u, y0, w1p, b1, W2, b2, (float*)d_out, mbox);
}